// Round 1
// baseline (200.440 us; speedup 1.0000x reference)
//
#include <hip/hip_runtime.h>

// DihedralTerm: E = sum_e force_e * (1 + cos(n_e * phi_e - phase_e))
// phi from 4 gathered atom positions (OpenMM convention).
//
// Key tricks:
//  - coords padded to float4 in d_ws so each gather is a single aligned
//    16B load (one cache line); coords fit in L2 (1.6 MB).
//  - no acosf/cosf on the main path: n is an integer in {1..4}, so
//    cos(n*phi - phase) = cos(n phi) cos(phase) + sin(n phi) sin(phase),
//    with (cos(n phi), sin(n phi)) by Chebyshev recurrence from
//    (cos phi, sin phi). cos phi = d * rsqrt(|c12|^2 |c23|^2),
//    sin phi = sign * sqrt(1 - cos^2). Only hw-trig: __sincos of phase.
//  - reduction: wave shfl -> LDS across waves -> one float atomicAdd/block.

__global__ __launch_bounds__(256) void pad_coords_kernel(
    const float* __restrict__ coords, float4* __restrict__ out, int n)
{
    int t = blockIdx.x * blockDim.x + threadIdx.x;
    if (t < n) {
        out[t] = make_float4(coords[3 * t + 0], coords[3 * t + 1],
                             coords[3 * t + 2], 0.0f);
    }
}

template <bool PADDED>
__global__ __launch_bounds__(256) void dihedral_kernel(
    const void* __restrict__ coords_v,
    const int* __restrict__ ii, const int* __restrict__ jj,
    const int* __restrict__ kk, const int* __restrict__ ll,
    const float* __restrict__ force, const float* __restrict__ period,
    const float* __restrict__ phase,
    float* __restrict__ out, int n)
{
    int t = blockIdx.x * blockDim.x + threadIdx.x;
    float e = 0.0f;
    if (t < n) {
        float p0x, p0y, p0z, p1x, p1y, p1z, p2x, p2y, p2z, p3x, p3y, p3z;
        if (PADDED) {
            const float4* c4 = (const float4*)coords_v;
            float4 a = c4[ii[t]], b = c4[jj[t]], c = c4[kk[t]], d = c4[ll[t]];
            p0x = a.x; p0y = a.y; p0z = a.z;
            p1x = b.x; p1y = b.y; p1z = b.z;
            p2x = c.x; p2y = c.y; p2z = c.z;
            p3x = d.x; p3y = d.y; p3z = d.z;
        } else {
            const float* cf = (const float*)coords_v;
            int a = ii[t], b = jj[t], c = kk[t], d = ll[t];
            p0x = cf[3 * a]; p0y = cf[3 * a + 1]; p0z = cf[3 * a + 2];
            p1x = cf[3 * b]; p1y = cf[3 * b + 1]; p1z = cf[3 * b + 2];
            p2x = cf[3 * c]; p2y = cf[3 * c + 1]; p2z = cf[3 * c + 2];
            p3x = cf[3 * d]; p3y = cf[3 * d + 1]; p3z = cf[3 * d + 2];
        }

        // Bond-like vectors
        float v1x = p0x - p1x, v1y = p0y - p1y, v1z = p0z - p1z;
        float v2x = p2x - p1x, v2y = p2y - p1y, v2z = p2z - p1z;
        float v3x = p2x - p3x, v3y = p2y - p3y, v3z = p2z - p3z;

        // cross12 = v1 x v2, cross23 = v2 x v3
        float ax = v1y * v2z - v1z * v2y;
        float ay = v1z * v2x - v1x * v2z;
        float az = v1x * v2y - v1y * v2x;
        float bx = v2y * v3z - v2z * v3y;
        float by = v2z * v3x - v2x * v3z;
        float bz = v2x * v3y - v2y * v3x;

        float d12 = ax * bx + ay * by + az * bz;
        float na2 = ax * ax + ay * ay + az * az;
        float nb2 = bx * bx + by * by + bz * bz;
        // cos_phi = d / (max(|a|,1e-12) * max(|b|,1e-12)) -> product clamp
        float m = fmaxf(na2 * nb2, 1e-24f);
        float cphi = d12 * __builtin_amdgcn_rsqf(m);
        cphi = fminf(fmaxf(cphi, -1.0f), 1.0f);
        float s2 = fmaxf(1.0f - cphi * cphi, 0.0f);
        float sphi = __builtin_amdgcn_sqrtf(s2);
        // sign from v1 . cross23
        float sdot = v1x * bx + v1y * by + v1z * bz;
        sphi = (sdot < 0.0f) ? -sphi : sphi;

        // n = |period|, integer in {1..4}; Chebyshev multiple-angle
        int np = (int)(fabsf(period[t]) + 0.5f);
        float cn = cphi, sn = sphi;
#pragma unroll
        for (int q = 1; q < 4; ++q) {
            float cnew = cn * cphi - sn * sphi;
            float snew = sn * cphi + cn * sphi;
            bool take = (q < np);
            cn = take ? cnew : cn;
            sn = take ? snew : sn;
        }

        float ph = phase[t];
        float cp = __cosf(ph);
        float sp = __sinf(ph);
        // cos(n*phi - phase) = cn*cp + sn*sp
        e = force[t] * (1.0f + cn * cp + sn * sp);
    }

    // --- block reduction: wave shfl -> LDS -> one atomicAdd ---
#pragma unroll
    for (int off = 32; off > 0; off >>= 1)
        e += __shfl_down(e, off, 64);

    __shared__ float wsum[4];
    int lane = threadIdx.x & 63;
    int wv = threadIdx.x >> 6;
    if (lane == 0) wsum[wv] = e;
    __syncthreads();
    if (threadIdx.x == 0) {
        float tot = wsum[0] + wsum[1] + wsum[2] + wsum[3];
        atomicAdd(out, tot);
    }
}

extern "C" void kernel_launch(void* const* d_in, const int* in_sizes, int n_in,
                              void* d_out, int out_size, void* d_ws, size_t ws_size,
                              hipStream_t stream) {
    const float* coords = (const float*)d_in[0];
    const int* ii = (const int*)d_in[1];
    const int* jj = (const int*)d_in[2];
    const int* kk = (const int*)d_in[3];
    const int* ll = (const int*)d_in[4];
    const float* force = (const float*)d_in[5];
    const float* period = (const float*)d_in[6];
    const float* phase = (const float*)d_in[7];

    int natoms = in_sizes[0] / 3;
    int n = in_sizes[1];
    float* out = (float*)d_out;

    // d_out is re-poisoned before every timed launch -> zero it on-stream.
    hipMemsetAsync(d_out, 0, (size_t)out_size * sizeof(float), stream);

    int blocks = (n + 255) / 256;
    size_t pad_bytes = (size_t)natoms * sizeof(float4);
    if (ws_size >= pad_bytes) {
        float4* c4 = (float4*)d_ws;
        pad_coords_kernel<<<(natoms + 255) / 256, 256, 0, stream>>>(coords, c4, natoms);
        dihedral_kernel<true><<<blocks, 256, 0, stream>>>(
            (const void*)c4, ii, jj, kk, ll, force, period, phase, out, n);
    } else {
        dihedral_kernel<false><<<blocks, 256, 0, stream>>>(
            (const void*)coords, ii, jj, kk, ll, force, period, phase, out, n);
    }
}

// Round 2
// 142.125 us; speedup vs baseline: 1.4103x; 1.4103x over previous
//
#include <hip/hip_runtime.h>

// DihedralTerm: E = sum_e force_e * (1 + cos(n_e * phi_e - phase_e))
//
// R2 changes vs R1:
//  - REMOVED the same-address atomicAdd (7813 blocks -> one L2 serialization
//    point; theory: that was ~100us of the 108us). Each block now writes its
//    partial sum to d_ws with a plain store; a second 1-block kernel reduces
//    the ~1954 partials into d_out.
//  - 4 items/thread (block covers 1024 contiguous elements) -> 4x the
//    outstanding loads per wave (MLP), 4x fewer waves/blocks.
//  - coords still padded to float4 in d_ws (single 16B aligned gather/atom,
//    table is 1.6 MB -> L2-resident).
//  - trig-free main path: integer period n in {1..4}; Chebyshev recurrence
//    from (cos phi, sin phi); only hw trig is __sincos of phase.

#define BLOCK 256
#define ITEMS 4
#define CHUNK (BLOCK * ITEMS)

__global__ __launch_bounds__(256) void pad_coords_kernel(
    const float* __restrict__ coords, float4* __restrict__ out, int n)
{
    int t = blockIdx.x * blockDim.x + threadIdx.x;
    if (t < n) {
        out[t] = make_float4(coords[3 * t + 0], coords[3 * t + 1],
                             coords[3 * t + 2], 0.0f);
    }
}

template <bool PADDED>
__global__ __launch_bounds__(BLOCK) void dihedral_kernel(
    const void* __restrict__ coords_v,
    const int* __restrict__ ii, const int* __restrict__ jj,
    const int* __restrict__ kk, const int* __restrict__ ll,
    const float* __restrict__ force, const float* __restrict__ period,
    const float* __restrict__ phase,
    float* __restrict__ partials, int n)
{
    int base = blockIdx.x * CHUNK + threadIdx.x;

    // ---- phase 1: issue all index loads (16 in flight) ----
    int ia[ITEMS], ib[ITEMS], ic[ITEMS], id[ITEMS];
#pragma unroll
    for (int q = 0; q < ITEMS; ++q) {
        int t = base + q * BLOCK;
        int ts = (t < n) ? t : 0;          // clamp; masked at accumulate
        ia[q] = ii[ts]; ib[q] = jj[ts]; ic[q] = kk[ts]; id[q] = ll[ts];
    }

    // ---- phase 2: issue all gathers (16 in flight) + param loads ----
    float4 P0[ITEMS], P1[ITEMS], P2[ITEMS], P3[ITEMS];
    float F[ITEMS], PN[ITEMS], PH[ITEMS];
    const float4* c4 = (const float4*)coords_v;
    const float* cf = (const float*)coords_v;
#pragma unroll
    for (int q = 0; q < ITEMS; ++q) {
        if (PADDED) {
            P0[q] = c4[ia[q]]; P1[q] = c4[ib[q]];
            P2[q] = c4[ic[q]]; P3[q] = c4[id[q]];
        } else {
            P0[q] = make_float4(cf[3*ia[q]], cf[3*ia[q]+1], cf[3*ia[q]+2], 0.f);
            P1[q] = make_float4(cf[3*ib[q]], cf[3*ib[q]+1], cf[3*ib[q]+2], 0.f);
            P2[q] = make_float4(cf[3*ic[q]], cf[3*ic[q]+1], cf[3*ic[q]+2], 0.f);
            P3[q] = make_float4(cf[3*id[q]], cf[3*id[q]+1], cf[3*id[q]+2], 0.f);
        }
        int t = base + q * BLOCK;
        int ts = (t < n) ? t : 0;
        F[q] = force[ts]; PN[q] = period[ts]; PH[q] = phase[ts];
    }

    // ---- phase 3: compute ----
    float e = 0.0f;
#pragma unroll
    for (int q = 0; q < ITEMS; ++q) {
        float v1x = P0[q].x - P1[q].x, v1y = P0[q].y - P1[q].y, v1z = P0[q].z - P1[q].z;
        float v2x = P2[q].x - P1[q].x, v2y = P2[q].y - P1[q].y, v2z = P2[q].z - P1[q].z;
        float v3x = P2[q].x - P3[q].x, v3y = P2[q].y - P3[q].y, v3z = P2[q].z - P3[q].z;

        float ax = v1y * v2z - v1z * v2y;
        float ay = v1z * v2x - v1x * v2z;
        float az = v1x * v2y - v1y * v2x;
        float bx = v2y * v3z - v2z * v3y;
        float by = v2z * v3x - v2x * v3z;
        float bz = v2x * v3y - v2y * v3x;

        float d12 = ax * bx + ay * by + az * bz;
        float na2 = ax * ax + ay * ay + az * az;
        float nb2 = bx * bx + by * by + bz * bz;
        float m = fmaxf(na2 * nb2, 1e-24f);
        float cphi = d12 * __builtin_amdgcn_rsqf(m);
        cphi = fminf(fmaxf(cphi, -1.0f), 1.0f);
        float s2 = fmaxf(1.0f - cphi * cphi, 0.0f);
        float sphi = __builtin_amdgcn_sqrtf(s2);
        float sdot = v1x * bx + v1y * by + v1z * bz;
        sphi = (sdot < 0.0f) ? -sphi : sphi;

        int np = (int)(fabsf(PN[q]) + 0.5f);
        float cn = cphi, sn = sphi;
#pragma unroll
        for (int r = 1; r < 4; ++r) {
            float cnew = cn * cphi - sn * sphi;
            float snew = sn * cphi + cn * sphi;
            bool take = (r < np);
            cn = take ? cnew : cn;
            sn = take ? snew : sn;
        }

        float cp = __cosf(PH[q]);
        float sp = __sinf(PH[q]);
        float val = F[q] * (1.0f + cn * cp + sn * sp);
        int t = base + q * BLOCK;
        e += (t < n) ? val : 0.0f;
    }

    // ---- block reduction: wave shfl -> LDS -> ONE PLAIN STORE per block ----
#pragma unroll
    for (int off = 32; off > 0; off >>= 1)
        e += __shfl_down(e, off, 64);

    __shared__ float wsum[BLOCK / 64];
    int lane = threadIdx.x & 63;
    int wv = threadIdx.x >> 6;
    if (lane == 0) wsum[wv] = e;
    __syncthreads();
    if (threadIdx.x == 0) {
        float tot = 0.0f;
#pragma unroll
        for (int w = 0; w < BLOCK / 64; ++w) tot += wsum[w];
        partials[blockIdx.x] = tot;
    }
}

__global__ __launch_bounds__(1024) void reduce_kernel(
    const float* __restrict__ partials, int m, float* __restrict__ out)
{
    float e = 0.0f;
    for (int i = threadIdx.x; i < m; i += 1024) e += partials[i];
#pragma unroll
    for (int off = 32; off > 0; off >>= 1)
        e += __shfl_down(e, off, 64);
    __shared__ float wsum[16];
    int lane = threadIdx.x & 63;
    int wv = threadIdx.x >> 6;
    if (lane == 0) wsum[wv] = e;
    __syncthreads();
    if (threadIdx.x == 0) {
        float tot = 0.0f;
#pragma unroll
        for (int w = 0; w < 16; ++w) tot += wsum[w];
        out[0] = tot;
    }
}

extern "C" void kernel_launch(void* const* d_in, const int* in_sizes, int n_in,
                              void* d_out, int out_size, void* d_ws, size_t ws_size,
                              hipStream_t stream) {
    const float* coords = (const float*)d_in[0];
    const int* ii = (const int*)d_in[1];
    const int* jj = (const int*)d_in[2];
    const int* kk = (const int*)d_in[3];
    const int* ll = (const int*)d_in[4];
    const float* force = (const float*)d_in[5];
    const float* period = (const float*)d_in[6];
    const float* phase = (const float*)d_in[7];

    int natoms = in_sizes[0] / 3;
    int n = in_sizes[1];
    float* out = (float*)d_out;

    int blocks = (n + CHUNK - 1) / CHUNK;

    size_t pad_bytes = (size_t)natoms * sizeof(float4);
    size_t part_off = (pad_bytes + 255) & ~(size_t)255;
    char* w = (char*)d_ws;

    if (ws_size >= part_off + (size_t)blocks * sizeof(float)) {
        float4* c4 = (float4*)w;
        float* partials = (float*)(w + part_off);
        pad_coords_kernel<<<(natoms + 255) / 256, 256, 0, stream>>>(coords, c4, natoms);
        dihedral_kernel<true><<<blocks, BLOCK, 0, stream>>>(
            (const void*)c4, ii, jj, kk, ll, force, period, phase, partials, n);
        reduce_kernel<<<1, 1024, 0, stream>>>(partials, blocks, out);
    } else {
        // fallback: no padded table, partials at ws start
        float* partials = (float*)w;
        dihedral_kernel<false><<<blocks, BLOCK, 0, stream>>>(
            (const void*)coords, ii, jj, kk, ll, force, period, phase, partials, n);
        reduce_kernel<<<1, 1024, 0, stream>>>(partials, blocks, out);
    }
}